// Round 1
// baseline (990.726 us; speedup 1.0000x reference)
//
#include <hip/hip_runtime.h>
#include <math.h>

#define NTOK   32768
#define DIM    2048
#define NE     256
#define NG     8
#define GSZ    32
#define NLIM   4
#define TOPK   8
#define RSCALE 2.5

#define BT      32   // tokens per block
#define KT      32   // K tile
#define THREADS 256

__global__ __launch_bounds__(THREADS) void router_kernel(
    const float* __restrict__ x, const float* __restrict__ w1,
    const float* __restrict__ b_lin, const float* __restrict__ bias,
    float* __restrict__ out_vals, float* __restrict__ out_idx)
{
    __shared__ union {
        struct {
            float xs[KT][BT + 1];  // [k][token], padded
            float ws[KT][NE];      // [k][expert]
        } t;
        double sc[NE][BT];         // scores, column-rotated by (t+e)&31
    } sm;

    const int tid = threadIdx.x;
    const int tx  = tid & 31;    // expert lane: e = tx + 32*j
    const int ty  = tid >> 5;    // token lane:  t = ty + 8*i
    const int t0  = blockIdx.x * BT;

    double acc[4][8];
#pragma unroll
    for (int i = 0; i < 4; ++i)
#pragma unroll
        for (int j = 0; j < 8; ++j) acc[i][j] = 0.0;

    for (int k0 = 0; k0 < DIM; k0 += KT) {
        __syncthreads();
        // stage x tile: 32 tokens x 32 k
        {
            const int r = tid >> 3, c = tid & 7;
            const float4 v = *reinterpret_cast<const float4*>(
                &x[(size_t)(t0 + r) * DIM + k0 + c * 4]);
            sm.t.xs[c * 4 + 0][r] = v.x;
            sm.t.xs[c * 4 + 1][r] = v.y;
            sm.t.xs[c * 4 + 2][r] = v.z;
            sm.t.xs[c * 4 + 3][r] = v.w;
        }
        // stage w tile: 256 experts x 32 k (thread == expert, conflict-free)
        {
            const float* wp = &w1[(size_t)tid * DIM + k0];
#pragma unroll
            for (int q = 0; q < 8; ++q) {
                const float4 v = *reinterpret_cast<const float4*>(wp + q * 4);
                sm.t.ws[q * 4 + 0][tid] = v.x;
                sm.t.ws[q * 4 + 1][tid] = v.y;
                sm.t.ws[q * 4 + 2][tid] = v.z;
                sm.t.ws[q * 4 + 3][tid] = v.w;
            }
        }
        __syncthreads();
#pragma unroll 4
        for (int k = 0; k < KT; ++k) {
            double xv[4], wv[8];
#pragma unroll
            for (int i = 0; i < 4; ++i) xv[i] = (double)sm.t.xs[k][ty + 8 * i];
#pragma unroll
            for (int j = 0; j < 8; ++j) wv[j] = (double)sm.t.ws[k][tx + 32 * j];
#pragma unroll
            for (int i = 0; i < 4; ++i)
#pragma unroll
                for (int j = 0; j < 8; ++j)
                    acc[i][j] = fma(xv[i], wv[j], acc[i][j]);
        }
    }

    // ---- epilogue: sigmoid + L1 normalize + bias, all fp64 ----
    double psum[4] = {0.0, 0.0, 0.0, 0.0};
#pragma unroll
    for (int i = 0; i < 4; ++i) {
#pragma unroll
        for (int j = 0; j < 8; ++j) {
            const int e = tx + 32 * j;
            const double l = acc[i][j] + (double)b_lin[e];
            const double s = 1.0 / (1.0 + exp(-l));
            acc[i][j] = s;
            psum[i] += s;
        }
    }
    // sum over 256 experts = reduce across the 32 tx-lanes (xor<=16 stays in half-wave)
#pragma unroll
    for (int m = 16; m >= 1; m >>= 1) {
#pragma unroll
        for (int i = 0; i < 4; ++i) psum[i] += __shfl_xor(psum[i], m, 64);
    }

    __syncthreads();  // tiles dead -> reuse LDS for scores
#pragma unroll
    for (int i = 0; i < 4; ++i) {
        const int tl = ty + 8 * i;
#pragma unroll
        for (int j = 0; j < 8; ++j) {
            const int e = tx + 32 * j;
            const double score = acc[i][j] / psum[i] + (double)bias[e];
            sm.sc[e][(tl + e) & 31] = score;
        }
    }
    __syncthreads();

    // ---- routing: one thread per token, exact jax tie-break semantics ----
    if (tid < BT) {
        const int t = tid;
        // group maxes
        double gmax[NG];
        for (int g = 0; g < NG; ++g) {
            double m = -INFINITY;
            for (int q = 0; q < GSZ; ++q) {
                const int e = g * GSZ + q;
                const double v = sm.sc[e][(t + e) & 31];
                m = (v > m) ? v : m;
            }
            gmax[g] = m;
        }
        // top-4 groups (strict >, ascending scan -> lower index wins ties)
        unsigned keep = 0u;
        for (int r = 0; r < NLIM; ++r) {
            int best = 0; double bv = -INFINITY;
            for (int g = 0; g < NG; ++g) {
                if (keep & (1u << g)) continue;
                if (gmax[g] > bv) { bv = gmax[g]; best = g; }
            }
            keep |= 1u << best;
        }
        // top-8 experts among kept groups (stable insertion, ascending e)
        double tv[TOPK]; int ti[TOPK];
        for (int r = 0; r < TOPK; ++r) { tv[r] = -INFINITY; ti[r] = NE; }
        for (int g = 0; g < NG; ++g) {
            if (!(keep & (1u << g))) continue;
            for (int q = 0; q < GSZ; ++q) {
                const int e = g * GSZ + q;
                const double v = sm.sc[e][(t + e) & 31];
                if (v > tv[TOPK - 1]) {
                    int p = TOPK - 1;
                    while (p > 0 && v > tv[p - 1]) {
                        tv[p] = tv[p - 1]; ti[p] = ti[p - 1]; --p;
                    }
                    tv[p] = v; ti[p] = e;
                }
            }
        }
        const size_t base = (size_t)(t0 + t) * TOPK;
        for (int r = 0; r < TOPK; ++r) {
            out_vals[base + r] = (float)(tv[r] * RSCALE);
            out_idx[base + r]  = (float)ti[r];
        }
    }
}

extern "C" void kernel_launch(void* const* d_in, const int* in_sizes, int n_in,
                              void* d_out, int out_size, void* d_ws, size_t ws_size,
                              hipStream_t stream) {
    const float* x     = (const float*)d_in[0];
    const float* w1    = (const float*)d_in[1];
    const float* b_lin = (const float*)d_in[2];
    const float* bias  = (const float*)d_in[3];
    float* out_vals = (float*)d_out;
    float* out_idx  = (float*)d_out + (size_t)NTOK * TOPK;

    dim3 grid(NTOK / BT);
    router_kernel<<<grid, THREADS, 0, stream>>>(x, w1, b_lin, bias,
                                                out_vals, out_idx);
}